// Round 6
// baseline (552.629 us; speedup 1.0000x reference)
//
#include <hip/hip_runtime.h>
#include <stdint.h>

#define H_DIM 256
#define NCOL 8192
#define TOPK 512
#define CAND_CAP 8192

typedef unsigned short u16;
typedef __attribute__((ext_vector_type(8))) __bf16 bf16x8;
typedef __attribute__((ext_vector_type(4))) float f32x4;
typedef unsigned __attribute__((address_space(3))) lds_u32;
typedef const unsigned __attribute__((address_space(1))) glb_u32;

// monotonic float -> uint key (order-preserving for all finite floats)
__device__ __forceinline__ unsigned fkey(float f) {
  unsigned u = __float_as_uint(f);
  unsigned m = (unsigned)((int)u >> 31) | 0x80000000u;
  return u ^ m;
}

__device__ __forceinline__ u16 f2bf_rne(float f) {
  unsigned u = __float_as_uint(f);
  return (u16)((u + 0x7fffu + ((u >> 16) & 1u)) >> 16);
}

__device__ __forceinline__ float bf2f(u16 h) {
  return __uint_as_float(((unsigned)h) << 16);
}

// ---------------- fused 2-layer MLP, both descriptor sets (grid 1024) ------------------
// blocks 0-511: set 0; 512-1023: set 1. block = 16 rows x 256 threads, thread owns 4x4.
// Layer-1 output h lives in LDS. fp32 fmaf chain order (d,d+1,d+2,d+3 sequential over K)
// is identical to the bitwise-exact path -> collect's exact-recompute guarantee holds.
__global__ __launch_bounds__(256) void mlp_fused(
    const float* __restrict__ X0, const float* __restrict__ W0a,
    const float* __restrict__ b0a, const float* __restrict__ W0b,
    const float* __restrict__ b0b, float* __restrict__ Y0,
    u16* __restrict__ h0, u16* __restrict__ l0,
    const float* __restrict__ X1, const float* __restrict__ W1a,
    const float* __restrict__ b1a, const float* __restrict__ W1b,
    const float* __restrict__ b1b, float* __restrict__ Y1,
    u16* __restrict__ h1, u16* __restrict__ l1,
    unsigned* __restrict__ ghist, unsigned* __restrict__ counter,
    unsigned* __restrict__ nwork) {
  __shared__ float Xs[16 * 128];  // 8KB
  __shared__ float Hs[16 * 256];  // 16KB
  const int t = threadIdx.x;
  if (blockIdx.x == 0) {  // folded zero_ws (completes before gemm/collect in stream order)
    for (int i = t; i < 4096; i += 256) ghist[i] = 0;
    if (t == 0) { *counter = 0; *nwork = 0; }
  }
  const int half = blockIdx.x >> 9;
  const float* X = half ? X1 : X0;
  const float* Wa = half ? W1a : W0a;
  const float* ba = half ? b1a : b0a;
  const float* Wb = half ? W1b : W0b;
  const float* bb_ = half ? b1b : b0b;
  float* Y = half ? Y1 : Y0;
  u16* hi = half ? h1 : h0;
  u16* lo = half ? l1 : l0;
  const int row0 = (blockIdx.x & 511) * 16;

  for (int f = t; f < 512; f += 256) {  // 16*128/4 float4s
    *(float4*)(Xs + f * 4) = *(const float4*)(X + (size_t)row0 * 128 + f * 4);
  }
  __syncthreads();
  const int cg = (t & 63) * 4;  // column base (0..252)
  const int rg = (t >> 6) * 4;  // local row base (0,4,8,12)

  // ---- layer 1: K=128, ReLU, output -> Hs ----
  {
    float acc[4][4];
#pragma unroll
    for (int r = 0; r < 4; r++)
#pragma unroll
      for (int c = 0; c < 4; c++) acc[r][c] = 0.f;
    for (int d = 0; d < 128; d += 4) {
      float4 w0 = *(const float4*)(Wa + (d + 0) * H_DIM + cg);
      float4 w1 = *(const float4*)(Wa + (d + 1) * H_DIM + cg);
      float4 w2 = *(const float4*)(Wa + (d + 2) * H_DIM + cg);
      float4 w3 = *(const float4*)(Wa + (d + 3) * H_DIM + cg);
#pragma unroll
      for (int r = 0; r < 4; r++) {
        float4 x = *(const float4*)(Xs + (rg + r) * 128 + d);  // wave-uniform broadcast
#pragma unroll
        for (int c = 0; c < 4; c++) {
          float a = acc[r][c];
          a = fmaf(x.x, ((const float*)&w0)[c], a);
          a = fmaf(x.y, ((const float*)&w1)[c], a);
          a = fmaf(x.z, ((const float*)&w2)[c], a);
          a = fmaf(x.w, ((const float*)&w3)[c], a);
          acc[r][c] = a;
        }
      }
    }
    const float4 bv = *(const float4*)(ba + cg);
#pragma unroll
    for (int r = 0; r < 4; r++) {
      float4 v;
      v.x = fmaxf(acc[r][0] + bv.x, 0.f);
      v.y = fmaxf(acc[r][1] + bv.y, 0.f);
      v.z = fmaxf(acc[r][2] + bv.z, 0.f);
      v.w = fmaxf(acc[r][3] + bv.w, 0.f);
      *(float4*)(Hs + (rg + r) * 256 + cg) = v;
    }
  }
  __syncthreads();

  // ---- layer 2: K=256 from Hs, emit fp32 + bf16 hi/lo split ----
  {
    float acc[4][4];
#pragma unroll
    for (int r = 0; r < 4; r++)
#pragma unroll
      for (int c = 0; c < 4; c++) acc[r][c] = 0.f;
    for (int d = 0; d < 256; d += 4) {
      float4 w0 = *(const float4*)(Wb + (d + 0) * H_DIM + cg);
      float4 w1 = *(const float4*)(Wb + (d + 1) * H_DIM + cg);
      float4 w2 = *(const float4*)(Wb + (d + 2) * H_DIM + cg);
      float4 w3 = *(const float4*)(Wb + (d + 3) * H_DIM + cg);
#pragma unroll
      for (int r = 0; r < 4; r++) {
        float4 x = *(const float4*)(Hs + (rg + r) * 256 + d);  // wave-uniform broadcast
#pragma unroll
        for (int c = 0; c < 4; c++) {
          float a = acc[r][c];
          a = fmaf(x.x, ((const float*)&w0)[c], a);
          a = fmaf(x.y, ((const float*)&w1)[c], a);
          a = fmaf(x.z, ((const float*)&w2)[c], a);
          a = fmaf(x.w, ((const float*)&w3)[c], a);
          acc[r][c] = a;
        }
      }
    }
    const float4 bv = *(const float4*)(bb_ + cg);
#pragma unroll
    for (int r = 0; r < 4; r++) {
      float4 v;
      v.x = acc[r][0] + bv.x;
      v.y = acc[r][1] + bv.y;
      v.z = acc[r][2] + bv.z;
      v.w = acc[r][3] + bv.w;
      const size_t grow = (size_t)(row0 + rg + r);
      *(float4*)(Y + grow * H_DIM + cg) = v;
      ushort4 hv, lv;
      hv.x = f2bf_rne(v.x); lv.x = f2bf_rne(v.x - bf2f(hv.x));
      hv.y = f2bf_rne(v.y); lv.y = f2bf_rne(v.y - bf2f(hv.y));
      hv.z = f2bf_rne(v.z); lv.z = f2bf_rne(v.z - bf2f(hv.z));
      hv.w = f2bf_rne(v.w); lv.w = f2bf_rne(v.w - bf2f(hv.w));
      *(ushort4*)(hi + grow * H_DIM + cg) = hv;
      *(ushort4*)(lo + grow * H_DIM + cg) = lv;
    }
  }
}

// ---------------- big GEMM (bf16x3), phase-split counted-vmcnt + subtile max map ----------
// 256x256 tile, 512 threads (8 waves, 2M x 4N), per-wave 128x64 output, K-chunks of 32.
// LDS row = 128B [Xh(32 bf16) | Xl(32 bf16)], XOR-swizzle byte ^= ((row&7)<<4) applied via
// inverse-swizzled per-lane global source (linear global_load_lds dest) + swizzled ds_read.
// Chunk skeleton: STAGE(next) -> vmcnt(8) -> barrier -> 3 phases (32 MFMA each) -> barrier.
// NEW: per 64x64 output subtile, the wave emits max(fkey) -> tilemax[128][128] so collect
// can skip subtiles that cannot contain a candidate (max >= member keys, fkey monotone).
__global__ __launch_bounds__(512, 2) void gemm_sim_mfma(const u16* __restrict__ Ah,
                                                        const u16* __restrict__ Al,
                                                        const u16* __restrict__ Bh,
                                                        const u16* __restrict__ Bl,
                                                        float* __restrict__ C,
                                                        unsigned* __restrict__ ghist,
                                                        unsigned* __restrict__ tilemax) {
  __shared__ __align__(16) char SB[131072];  // 2 bufs x (A2 32KB + B2 32KB)
  const int t = threadIdx.x;
  const int wave = t >> 6, lane = t & 63;
  const int wm = wave >> 2, wn = wave & 3;  // 2M x 4N waves
  // XCD swizzle: 1024 blocks, 1024%8==0 -> bijective
  const int bid = blockIdx.x;
  const int swz = (bid & 7) * 128 + (bid >> 3);
  const int m0 = (swz >> 5) * 256, n0 = (swz & 31) * 256;

  f32x4 acc[8][4];
#pragma unroll
  for (int i = 0; i < 8; i++)
#pragma unroll
    for (int j = 0; j < 4; j++) acc[i][j] = (f32x4){0.f, 0.f, 0.f, 0.f};

  // staging: round i covers LDS bytes [i*8192,+8192): row = i*64 + (t>>3), slot = t&7.
  // source slot = slot ^ (row&7) (involution); slots 0-3 -> Xh, 4-7 -> Xl.
  const int srow8 = t >> 3;
  const int sA = (t & 7) ^ (srow8 & 7);
  const u16* pAsrc = (sA < 4) ? Ah : Al;
  const u16* pBsrc = (sA < 4) ? Bh : Bl;
  const int scolE = (sA & 3) * 8;  // elems within the 32-elem k-chunk
  // fragment read: row lrow in 16-row group, k-group byte kq16; swizzle key = lrow&7
  const int lrow = lane & 15;
  const int kq16 = (lane >> 4) << 4;
  const int asz = (lrow & 7) << 4;
  const int cH = kq16 ^ asz;         // hi operand col byte within 128B row
  const int cL = (64 + kq16) ^ asz;  // lo operand col byte

  auto STAGE = [&](int bsel, int tt) {
    const int kofs = tt * 32;
    char* base = SB + bsel * 65536;
    const size_t ar = (size_t)(m0 + srow8) * H_DIM + kofs + scolE;
    const size_t br = (size_t)(n0 + srow8) * H_DIM + kofs + scolE;
#pragma unroll
    for (int i = 0; i < 4; i++)
      __builtin_amdgcn_global_load_lds((glb_u32*)(pAsrc + ar + (size_t)i * 64 * H_DIM),
                                       (lds_u32*)(base + i * 8192 + wave * 1024), 16, 0, 0);
#pragma unroll
    for (int i = 0; i < 4; i++)
      __builtin_amdgcn_global_load_lds((glb_u32*)(pBsrc + br + (size_t)i * 64 * H_DIM),
                                       (lds_u32*)(base + 32768 + i * 8192 + wave * 1024), 16, 0, 0);
  };

  STAGE(0, 0);
  for (int tt = 0; tt < 8; ++tt) {
    if (tt < 7) {
      STAGE((tt + 1) & 1, tt + 1);
      asm volatile("s_waitcnt vmcnt(8)" ::: "memory");  // chunk tt staged; tt+1 in flight
    } else {
      asm volatile("s_waitcnt vmcnt(0)" ::: "memory");
    }
    __builtin_amdgcn_s_barrier();  // buf[tt&1] ready, all waves aligned
    asm volatile("" ::: "memory");
    const char* bb = SB + (tt & 1) * 65536;
    const char* bA = bb + (wm * 128 + lrow) * 128;
    const char* bB = bb + 32768 + (wn * 64 + lrow) * 128;

    // phase 1: read aH,bH; MFMA aH x bH
    bf16x8 aH[8], bH[4];
#pragma unroll
    for (int fm = 0; fm < 8; fm++) aH[fm] = *(const bf16x8*)(bA + fm * 2048 + cH);
#pragma unroll
    for (int fn = 0; fn < 4; fn++) bH[fn] = *(const bf16x8*)(bB + fn * 2048 + cH);
    __builtin_amdgcn_s_setprio(1);
#pragma unroll
    for (int fm = 0; fm < 8; fm++)
#pragma unroll
      for (int fn = 0; fn < 4; fn++)
        acc[fm][fn] = __builtin_amdgcn_mfma_f32_16x16x32_bf16(aH[fm], bH[fn], acc[fm][fn], 0, 0, 0);
    __builtin_amdgcn_s_setprio(0);
    __builtin_amdgcn_s_barrier();  // scheduling barrier (no buffer hazard within chunk)

    // phase 2: read bL; MFMA aH x bL
    {
      bf16x8 bL[4];
#pragma unroll
      for (int fn = 0; fn < 4; fn++) bL[fn] = *(const bf16x8*)(bB + fn * 2048 + cL);
      __builtin_amdgcn_s_setprio(1);
#pragma unroll
      for (int fm = 0; fm < 8; fm++)
#pragma unroll
        for (int fn = 0; fn < 4; fn++)
          acc[fm][fn] = __builtin_amdgcn_mfma_f32_16x16x32_bf16(aH[fm], bL[fn], acc[fm][fn], 0, 0, 0);
      __builtin_amdgcn_s_setprio(0);
    }
    __builtin_amdgcn_s_barrier();

    // phase 3: read aL; MFMA aL x bH
    {
      bf16x8 aL[8];
#pragma unroll
      for (int fm = 0; fm < 8; fm++) aL[fm] = *(const bf16x8*)(bA + fm * 2048 + cL);
      __builtin_amdgcn_s_setprio(1);
#pragma unroll
      for (int fm = 0; fm < 8; fm++)
#pragma unroll
        for (int fn = 0; fn < 4; fn++)
          acc[fm][fn] = __builtin_amdgcn_mfma_f32_16x16x32_bf16(aL[fm], bH[fn], acc[fm][fn], 0, 0, 0);
      __builtin_amdgcn_s_setprio(0);
    }
    __builtin_amdgcn_s_barrier();  // chunk end: all waves done reading buf[tt&1]
    asm volatile("" ::: "memory");
  }

  // ---------- per-wave 64x64 subtile max -> tilemax (for collect pruning) ----------
  {
    float mx0 = -3.4e38f, mx1 = -3.4e38f;
#pragma unroll
    for (int fm = 0; fm < 4; fm++)
#pragma unroll
      for (int fn = 0; fn < 4; fn++)
#pragma unroll
        for (int q = 0; q < 4; q++) {
          mx0 = fmaxf(mx0, acc[fm][fn][q]);
          mx1 = fmaxf(mx1, acc[fm + 4][fn][q]);
        }
#pragma unroll
    for (int off = 1; off < 64; off <<= 1) {
      mx0 = fmaxf(mx0, __shfl_xor(mx0, off, 64));
      mx1 = fmaxf(mx1, __shfl_xor(mx1, off, 64));
    }
    if (lane == 0) {
      const int str = (m0 >> 6) + wm * 2, stc = (n0 >> 6) + wn;
      tilemax[str * 128 + stc] = fkey(mx0);
      tilemax[(str + 1) * 128 + stc] = fkey(mx1);
    }
  }

  // ---------- epilogue: LDS-staged coalesced C-store + histogram ----------
  // C/D frag layout: col=lane&15, row=(lane>>4)*4+q (m89-verified).
  unsigned* hist = (unsigned*)SB;    // 16KB
  float* Ct = (float*)(SB + 16384);  // [64][260] fp32, pad 4
  for (int i = t; i < 4096; i += 512) hist[i] = 0;
  __syncthreads();
#pragma unroll
  for (int ch = 0; ch < 4; ++ch) {  // 64-row chunks of the 256-row tile
    if (wm == (ch >> 1)) {
      const int fmb = (ch & 1) * 4;
#pragma unroll
      for (int fi = 0; fi < 4; fi++)
#pragma unroll
        for (int fn = 0; fn < 4; fn++)
#pragma unroll
          for (int q = 0; q < 4; q++)
            Ct[(fi * 16 + (lane >> 4) * 4 + q) * 260 + wn * 64 + fn * 16 + lrow] =
                acc[fmb + fi][fn][q];
    }
    __syncthreads();
#pragma unroll
    for (int u = 0; u < 8; ++u) {
      const int idx = t + u * 512;  // 4096 float4 = 64x256 floats
      const int row = idx >> 6, c4 = idx & 63;
      float4 v = *(const float4*)(Ct + row * 260 + c4 * 4);
      *(float4*)(C + (size_t)(m0 + ch * 64 + row) * NCOL + n0 + c4 * 4) = v;
      atomicAdd(&hist[fkey(v.x) >> 20], 1u);
      atomicAdd(&hist[fkey(v.y) >> 20], 1u);
      atomicAdd(&hist[fkey(v.z) >> 20], 1u);
      atomicAdd(&hist[fkey(v.w) >> 20], 1u);
    }
    __syncthreads();
  }
  for (int bq = t; bq < 4096; bq += 512) {
    unsigned cc = hist[bq];
    if (cc) atomicAdd(&ghist[bq], cc);
  }
}

// ---------------- collect_scan: threshold from ghist + worklist of candidate subtiles ----
// Threshold semantics identical to prior rounds: smallest bin b* with
// count(key >= b*<<20) >= TOPK; thr_m = thr - 4096 (bf16x3 error margin, ~2x absmax).
// A subtile can contain a key >= thr_m only if its max key >= thr_m (fkey monotone).
__global__ __launch_bounds__(256) void collect_scan(const unsigned* __restrict__ ghist,
                                                    const unsigned* __restrict__ tilemax,
                                                    unsigned* __restrict__ thrm_out,
                                                    int* __restrict__ worklist,
                                                    unsigned* __restrict__ nwork) {
  __shared__ unsigned part[256];
  __shared__ unsigned thr_sh;
  const int t = threadIdx.x;
  unsigned s = 0;
#pragma unroll
  for (int b = 0; b < 16; b++) s += ghist[t * 16 + b];
  part[t] = s;
  __syncthreads();
  for (int off = 1; off < 256; off <<= 1) {  // suffix sums over 16-bin groups
    unsigned v = part[t] + ((t + off < 256) ? part[t + off] : 0u);
    __syncthreads();
    part[t] = v;
    __syncthreads();
  }
  if (part[t] >= TOPK && (t == 255 || part[t + 1] < TOPK)) {
    unsigned cum = (t == 255) ? 0u : part[t + 1];
    int bsel = t * 16;
    for (int b = t * 16 + 15; b >= t * 16; --b) {
      cum += ghist[b];
      if (cum >= TOPK) { bsel = b; break; }
    }
    thr_sh = (unsigned)bsel << 20;
  }
  __syncthreads();
  const unsigned thr = thr_sh;
  const unsigned thr_m = thr > 4096u ? thr - 4096u : 0u;
  if (t == 0) *thrm_out = thr_m;
  for (int i = t; i < 16384; i += 256) {
    if (tilemax[i] >= thr_m) {
      unsigned p = atomicAdd(nwork, 1u);
      worklist[p] = i;
    }
  }
}

// ---------------- collect_gather: scan only flagged 64x64 subtiles, exact recompute --------
__device__ __forceinline__ void cand_push(unsigned kapprox, unsigned thr_m, unsigned idx,
                                          const float* __restrict__ m0f,
                                          const float* __restrict__ m1f,
                                          unsigned long long* __restrict__ cand,
                                          unsigned* __restrict__ counter) {
  if (kapprox >= thr_m) {
    const unsigned row = idx >> 13;   // /8192
    const unsigned col = idx & 8191u; // %8192
    const float4* a4 = (const float4*)(m0f + (size_t)row * H_DIM);
    const float4* b4 = (const float4*)(m1f + (size_t)col * H_DIM);
    float v = 0.f;
#pragma unroll 8
    for (int k = 0; k < H_DIM / 4; k++) {
      float4 a = a4[k], b = b4[k];
      v = fmaf(a.x, b.x, v);
      v = fmaf(a.y, b.y, v);
      v = fmaf(a.z, b.z, v);
      v = fmaf(a.w, b.w, v);
    }
    unsigned p = atomicAdd(counter, 1u);
    if (p < CAND_CAP)
      cand[p] = ((unsigned long long)fkey(v) << 32) |
                (unsigned long long)(0xFFFFFFFFu - idx);
  }
}

__global__ __launch_bounds__(256) void collect_gather(const float* __restrict__ sim,
                                                      const unsigned* __restrict__ thrm_p,
                                                      const int* __restrict__ worklist,
                                                      const unsigned* __restrict__ nwork,
                                                      const float* __restrict__ m0f,
                                                      const float* __restrict__ m1f,
                                                      unsigned long long* __restrict__ cand,
                                                      unsigned* __restrict__ counter) {
  const unsigned thr_m = *thrm_p;
  const int nw = (int)*nwork;
  const int t = threadIdx.x;
  for (int w = blockIdx.x; w < nw; w += gridDim.x) {
    const int sid = worklist[w];
    const int r0 = (sid >> 7) << 6, c0 = (sid & 127) << 6;
    const float4* base = (const float4*)(sim + (size_t)r0 * NCOL + c0);
#pragma unroll
    for (int u = 0; u < 4; ++u) {
      const int f = t + u * 256;  // 1024 float4 = 64x64 floats
      const int row = f >> 4, q4 = f & 15;
      float4 v = base[(size_t)row * (NCOL / 4) + q4];
      const unsigned gidx = (unsigned)(r0 + row) * NCOL + c0 + q4 * 4;
      cand_push(fkey(v.x), thr_m, gidx + 0u, m0f, m1f, cand, counter);
      cand_push(fkey(v.y), thr_m, gidx + 1u, m0f, m1f, cand, counter);
      cand_push(fkey(v.z), thr_m, gidx + 2u, m0f, m1f, cand, counter);
      cand_push(fkey(v.w), thr_m, gidx + 3u, m0f, m1f, cand, counter);
    }
  }
}

// ---------------- top-512: register-resident radix-select (exact 512th key) + 512-sort ----
// Keys are distinct 64-bit (idx in low bits) -> exact kth, no ties. Order matches
// jax.lax.top_k: descending by value; equal values -> smaller idx first via the
// (0xFFFFFFFF - idx) low field.
__global__ __launch_bounds__(1024) void sort_topk(const unsigned long long* __restrict__ cand,
                                                  const unsigned* __restrict__ counter,
                                                  float* __restrict__ out) {
  __shared__ unsigned long long top[TOPK];
  __shared__ unsigned wred[16];
  __shared__ unsigned long long pfx_sh;
  __shared__ unsigned cnt_sh;
  const int t = threadIdx.x;
  const int n = (int)min(*counter, (unsigned)CAND_CAP);
  unsigned long long e[CAND_CAP / 1024];
#pragma unroll
  for (int u = 0; u < CAND_CAP / 1024; ++u) {
    const int i = t + u * 1024;
    e[u] = (i < n) ? cand[i] : 0ULL;
  }
  if (t == 0) cnt_sh = 0;
  __syncthreads();
  // bitwise binary search for the 512th-largest key (max p with #{e >= p} >= 512)
  unsigned long long pfx = 0;
  for (int b = 63; b >= 0; --b) {
    const unsigned long long q = pfx | (1ULL << b);
    unsigned c = 0;
#pragma unroll
    for (int u = 0; u < CAND_CAP / 1024; ++u) c += (e[u] >= q) ? 1u : 0u;
#pragma unroll
    for (int off = 32; off; off >>= 1) c += __shfl_down(c, off, 64);
    if ((t & 63) == 0) wred[t >> 6] = c;
    __syncthreads();
    if (t == 0) {
      unsigned tot = 0;
#pragma unroll
      for (int w = 0; w < 16; ++w) tot += wred[w];
      pfx_sh = (tot >= TOPK) ? q : pfx;
    }
    __syncthreads();
    pfx = pfx_sh;
  }
  // compact: exactly TOPK elements are >= pfx (distinct keys)
#pragma unroll
  for (int u = 0; u < CAND_CAP / 1024; ++u) {
    if (e[u] >= pfx) {
      unsigned p = atomicAdd(&cnt_sh, 1u);
      if (p < TOPK) top[p] = e[u];
    }
  }
  __syncthreads();
  // bitonic sort 512, descending
  for (int k = 2; k <= TOPK; k <<= 1) {
    for (int j = k >> 1; j > 0; j >>= 1) {
      if (t < TOPK) {
        const int l = t ^ j;
        if (l > t) {
          const bool desc = ((t & k) == 0);
          unsigned long long a = top[t], b2 = top[l];
          if (desc ? (a < b2) : (a > b2)) { top[t] = b2; top[l] = a; }
        }
      }
      __syncthreads();
    }
  }
  if (t < TOPK) {
    const unsigned idx = 0xFFFFFFFFu - (unsigned)(top[t] & 0xFFFFFFFFull);
    out[t * 2 + 0] = (float)(idx >> 13);   // row
    out[t * 2 + 1] = (float)(idx & 8191u); // col
  }
}

extern "C" void kernel_launch(void* const* d_in, const int* in_sizes, int n_in,
                              void* d_out, int out_size, void* d_ws, size_t ws_size,
                              hipStream_t stream) {
  const float* desc0 = (const float*)d_in[0];
  const float* desc1 = (const float*)d_in[1];
  const float* W0a = (const float*)d_in[2];
  const float* b0a = (const float*)d_in[3];
  const float* W0b = (const float*)d_in[4];
  const float* b0b = (const float*)d_in[5];
  const float* W1a = (const float*)d_in[6];
  const float* b1a = (const float*)d_in[7];
  const float* W1b = (const float*)d_in[8];
  const float* b1b = (const float*)d_in[9];

  char* ws = (char*)d_ws;
  unsigned* ghist = (unsigned*)ws;                                  // 16KB
  unsigned* counter = (unsigned*)(ws + 16384);                     // 4B
  unsigned* thrm = (unsigned*)(ws + 16388);                        // 4B
  unsigned* nwork = (unsigned*)(ws + 16392);                       // 4B
  unsigned long long* cand = (unsigned long long*)(ws + 16448);    // 64KB
  unsigned* tilemax = (unsigned*)(ws + 98304);                     // 64KB (128x128 subtiles)
  int* worklist = (int*)(ws + 163840);                             // 64KB
  float* mdesc0f = (float*)(ws + 262144);                          // 8MB fp32 (exact recompute)
  float* mdesc1f = mdesc0f + 8192 * 256;                           // 8MB
  u16* Ahh = (u16*)(mdesc1f + 8192 * 256);                         // 4MB bf16 hi
  u16* All = Ahh + 8192 * 256;                                     // 4MB bf16 lo
  u16* Bhh = All + 8192 * 256;                                     // 4MB
  u16* Bll = Bhh + 8192 * 256;                                     // 4MB  (total ~32.3MB)

  float* outf = (float*)d_out;
  float* sim = outf + TOPK * 2;  // sim at float offset 1024 (16B aligned)

  mlp_fused<<<1024, 256, 0, stream>>>(
      desc0, W0a, b0a, W0b, b0b, mdesc0f, Ahh, All,
      desc1, W1a, b1a, W1b, b1b, mdesc1f, Bhh, Bll, ghist, counter, nwork);

  gemm_sim_mfma<<<1024, 512, 0, stream>>>(Ahh, All, Bhh, Bll, sim, ghist, tilemax);
  collect_scan<<<1, 256, 0, stream>>>(ghist, tilemax, thrm, worklist, nwork);
  collect_gather<<<1024, 256, 0, stream>>>(sim, thrm, worklist, nwork, mdesc0f, mdesc1f,
                                           cand, counter);
  sort_topk<<<1, 1024, 0, stream>>>(cand, counter, outf);
}